// Round 11
// baseline (838.621 us; speedup 1.0000x reference)
//
#include <hip/hip_runtime.h>
#include <hip/hip_bf16.h>

// B=2, L=4096, D=512, H=8, Hd=64, causal MHA, outputs (out, attn) fp32.

typedef __attribute__((ext_vector_type(8))) __bf16 bf16x8;
typedef __attribute__((ext_vector_type(4))) __bf16 bf16v4;
typedef __attribute__((ext_vector_type(4))) float f32x4;

constexpr int LL = 4096;
constexpr int DD = 512;
constexpr int HH = 8;
constexpr int HD = 64;
constexpr int BB = 2;
constexpr int BL = BB * LL;
constexpr size_t OUT_ELEMS = (size_t)BB * LL * DD;
constexpr size_t ATTN_ELEMS = (size_t)BB * HH * LL * LL;

static __device__ inline bf16x8 cvt8(const float* p) {
    float4 a = *reinterpret_cast<const float4*>(p);
    float4 b = *reinterpret_cast<const float4*>(p + 4);
    bf16x8 r;
    r[0] = (__bf16)a.x; r[1] = (__bf16)a.y; r[2] = (__bf16)a.z; r[3] = (__bf16)a.w;
    r[4] = (__bf16)b.x; r[5] = (__bf16)b.y; r[6] = (__bf16)b.z; r[7] = (__bf16)b.w;
    return r;
}

// ---------------------------------------------------------------------------
// Kernel 0: fp32 -> bf16 prepack of the three inputs.
// ---------------------------------------------------------------------------
__global__ __launch_bounds__(256) void cvt_kernel(
    const float* __restrict__ q, const float* __restrict__ k,
    const float* __restrict__ v, __bf16* __restrict__ o)
{
    constexpr size_t N = (size_t)BL * DD;
    size_t i = ((size_t)blockIdx.x * 256 + threadIdx.x) * 8;
    const float* src = q; size_t j = i;
    if (i >= 2 * N)      { src = v; j = i - 2 * N; }
    else if (i >= N)     { src = k; j = i - N; }
    *reinterpret_cast<bf16x8*>(&o[i]) = cvt8(&src[j]);
}

// ---------------------------------------------------------------------------
// Kernel 1: QKV projection from bf16 inputs. y = x @ W.T + b, bf16 out.
// z=0 -> Q [B,H,L,64]; z=1 -> K [B,H,L,64]; z=2 -> V^T [B,H,64,L].
// grid (BL/64, 8, 3), block 256.
// ---------------------------------------------------------------------------
__global__ __launch_bounds__(256) void qkv_kernel(
    const __bf16* __restrict__ Xb,
    const float* __restrict__ Wq, const float* __restrict__ bq,
    const float* __restrict__ Wk, const float* __restrict__ bk,
    const float* __restrict__ Wv, const float* __restrict__ bv,
    __bf16* __restrict__ Qb, __bf16* __restrict__ Kb, __bf16* __restrict__ Vt)
{
    const int z = blockIdx.z;
    const __bf16* x  = Xb + (size_t)z * BL * DD;
    const float* W   = (z == 0) ? Wq : (z == 1) ? Wk : Wv;
    const float* bia = (z == 0) ? bq : (z == 1) ? bk : bv;

    const int wid = threadIdx.x >> 6;
    const int lane = threadIdx.x & 63;
    const int l15 = lane & 15;
    const int lg  = lane >> 4;

    const int r0 = blockIdx.x * 64;
    const int cb = blockIdx.y;
    const int c0 = cb * 64 + wid * 16;

    f32x4 acc[4] = {};
    for (int k0 = 0; k0 < DD; k0 += 32) {
        bf16x8 bfrag = cvt8(&W[(size_t)(c0 + l15) * DD + k0 + lg * 8]);
#pragma unroll
        for (int mt = 0; mt < 4; ++mt) {
            bf16x8 afrag = *reinterpret_cast<const bf16x8*>(
                &x[(size_t)(r0 + mt * 16 + l15) * DD + k0 + lg * 8]);
            acc[mt] = __builtin_amdgcn_mfma_f32_16x16x32_bf16(afrag, bfrag, acc[mt], 0, 0, 0);
        }
    }

    __shared__ __bf16 T[64][72];
    const float bval = bia[c0 + l15];
#pragma unroll
    for (int mt = 0; mt < 4; ++mt)
#pragma unroll
        for (int i = 0; i < 4; ++i) {
            const float val = acc[mt][i] + bval;
            const int row = mt * 16 + lg * 4 + i;
            const int col = wid * 16 + l15;
            if (z == 2) T[col][row] = (__bf16)val;
            else        T[row][col] = (__bf16)val;
        }
    __syncthreads();

    const int tr  = threadIdx.x >> 2;
    const int seg = threadIdx.x & 3;
    uint4 v0 = *reinterpret_cast<const uint4*>(&T[tr][seg * 16]);
    uint4 v1 = *reinterpret_cast<const uint4*>(&T[tr][seg * 16 + 8]);
    const int b  = r0 >> 12;
    const int l0 = r0 & (LL - 1);
    if (z == 2) {
        __bf16* dst = Vt + ((size_t)(b * HH + cb) * HD + tr) * LL + l0 + seg * 16;
        *reinterpret_cast<uint4*>(dst)     = v0;
        *reinterpret_cast<uint4*>(dst + 8) = v1;
    } else {
        __bf16* base = (z == 0) ? Qb : Kb;
        __bf16* dst = base + ((size_t)(b * HH + cb) * LL + l0 + tr) * HD + seg * 16;
        *reinterpret_cast<uint4*>(dst)     = v0;
        *reinterpret_cast<uint4*>(dst + 8) = v1;
    }
}

// ---------------------------------------------------------------------------
// Kernel 2: FUSED causal attention (value writes only; zeros via memset).
// One WG per (bh, qb) 64-row block, wave w owns rows w*16..+15.
// Pass 1: swapped QK (mfma(K,Q)) + exp -> row sums (2 shfl reduce).
// Pass 2: recompute QK, normalized P, direct fp32 attn store, PV via
// wave-private LDS P tile. Epilogue: O -> Ob bf16.
// grid (16 bh, 64 qb-desc), block 256.
// ---------------------------------------------------------------------------
__global__ __launch_bounds__(256) void attn_fused_kernel(
    const __bf16* __restrict__ Qb, const __bf16* __restrict__ Kb,
    const __bf16* __restrict__ Vt, __bf16* __restrict__ Ob,
    float* __restrict__ attn_out)
{
    const int bh = blockIdx.x;
    const int qb = 63 - blockIdx.y;          // heavy WGs dispatch first

    const int wv   = threadIdx.x >> 6;
    const int lane = threadIdx.x & 63;
    const int l15  = lane & 15;
    const int lg   = lane >> 4;

    float* A_out = attn_out + (size_t)bh * LL * LL;
    const int q0 = qb * 64 + wv * 16;
    const int qrow = q0 + l15;

    const __bf16* Qh = Qb + (size_t)bh * LL * HD;
    const __bf16* Kh = Kb + (size_t)bh * LL * HD;
    const __bf16* Vh = Vt + (size_t)bh * HD * LL;

    __shared__ __bf16 P[4][16][72];          // wave-private P tile

    const bf16x8 qf0 = *reinterpret_cast<const bf16x8*>(&Qh[(size_t)qrow * HD + lg * 8]);
    const bf16x8 qf1 = *reinterpret_cast<const bf16x8*>(&Qh[(size_t)qrow * HD + 32 + lg * 8]);
    const float SC = 0.125f * 1.44269504088896f;   // scale * log2(e)

    // ---- pass 1: row sums ----
    float rs = 0.f;
    for (int kb = 0; kb <= qb; ++kb) {
        const __bf16* kp = &Kh[((size_t)kb * 64 + l15) * HD + lg * 8];
        f32x4 s[4] = {};
#pragma unroll
        for (int kt = 0; kt < 4; ++kt) {
            bf16x8 k0 = *reinterpret_cast<const bf16x8*>(kp + (size_t)kt * 16 * HD);
            bf16x8 k1 = *reinterpret_cast<const bf16x8*>(kp + (size_t)kt * 16 * HD + 32);
            s[kt] = __builtin_amdgcn_mfma_f32_16x16x32_bf16(k0, qf0, s[kt], 0, 0, 0);
            s[kt] = __builtin_amdgcn_mfma_f32_16x16x32_bf16(k1, qf1, s[kt], 0, 0, 0);
        }
        const bool diag = (kb == qb);
#pragma unroll
        for (int kt = 0; kt < 4; ++kt)
#pragma unroll
            for (int i = 0; i < 4; ++i) {
                float e = exp2f(s[kt][i] * SC);
                if (diag && (kb * 64 + kt * 16 + lg * 4 + i) > qrow) e = 0.f;
                rs += e;
            }
    }
    rs += __shfl_xor(rs, 16, 64);
    rs += __shfl_xor(rs, 32, 64);
    const float llog = -log2f(rs);

    // ---- pass 2: attn value write + PV ----
    f32x4 oacc[4] = {};
    for (int kb = 0; kb <= qb; ++kb) {
        const __bf16* kp = &Kh[((size_t)kb * 64 + l15) * HD + lg * 8];
        const __bf16* vp = &Vh[(size_t)l15 * LL + (size_t)kb * 64 + lg * 8];
        // V loads issue first; consumed after the P chain
        bf16x8 vf0 = *reinterpret_cast<const bf16x8*>(vp + (size_t)0 * 16 * LL);
        bf16x8 vf1 = *reinterpret_cast<const bf16x8*>(vp + (size_t)0 * 16 * LL + 32);
        bf16x8 vf2 = *reinterpret_cast<const bf16x8*>(vp + (size_t)1 * 16 * LL);
        bf16x8 vf3 = *reinterpret_cast<const bf16x8*>(vp + (size_t)1 * 16 * LL + 32);
        bf16x8 vf4 = *reinterpret_cast<const bf16x8*>(vp + (size_t)2 * 16 * LL);
        bf16x8 vf5 = *reinterpret_cast<const bf16x8*>(vp + (size_t)2 * 16 * LL + 32);
        bf16x8 vf6 = *reinterpret_cast<const bf16x8*>(vp + (size_t)3 * 16 * LL);
        bf16x8 vf7 = *reinterpret_cast<const bf16x8*>(vp + (size_t)3 * 16 * LL + 32);

        f32x4 s[4] = {};
#pragma unroll
        for (int kt = 0; kt < 4; ++kt) {
            bf16x8 k0 = *reinterpret_cast<const bf16x8*>(kp + (size_t)kt * 16 * HD);
            bf16x8 k1 = *reinterpret_cast<const bf16x8*>(kp + (size_t)kt * 16 * HD + 32);
            s[kt] = __builtin_amdgcn_mfma_f32_16x16x32_bf16(k0, qf0, s[kt], 0, 0, 0);
            s[kt] = __builtin_amdgcn_mfma_f32_16x16x32_bf16(k1, qf1, s[kt], 0, 0, 0);
        }
        const bool diag = (kb == qb);
#pragma unroll
        for (int kt = 0; kt < 4; ++kt) {
            float e0 = exp2f(fmaf(s[kt][0], SC, llog));
            float e1 = exp2f(fmaf(s[kt][1], SC, llog));
            float e2 = exp2f(fmaf(s[kt][2], SC, llog));
            float e3 = exp2f(fmaf(s[kt][3], SC, llog));
            if (diag) {
                const int kc = kb * 64 + kt * 16 + lg * 4;
                if (kc + 0 > qrow) e0 = 0.f;
                if (kc + 1 > qrow) e1 = 0.f;
                if (kc + 2 > qrow) e2 = 0.f;
                if (kc + 3 > qrow) e3 = 0.f;
            }
            // direct fp32 attn store (lane-local row, 16B per lane)
            f32x4 ev = {e0, e1, e2, e3};
            *reinterpret_cast<f32x4*>(
                &A_out[(size_t)qrow * LL + kb * 64 + kt * 16 + lg * 4]) = ev;
            // bf16 pack for PV
            bf16v4 pk;
            pk[0] = (__bf16)e0; pk[1] = (__bf16)e1;
            pk[2] = (__bf16)e2; pk[3] = (__bf16)e3;
            *reinterpret_cast<bf16v4*>(&P[wv][l15][kt * 16 + lg * 4]) = pk;
        }
        const bf16x8 pa0 = *reinterpret_cast<const bf16x8*>(&P[wv][l15][lg * 8]);
        const bf16x8 pa1 = *reinterpret_cast<const bf16x8*>(&P[wv][l15][32 + lg * 8]);
        oacc[0] = __builtin_amdgcn_mfma_f32_16x16x32_bf16(pa0, vf0, oacc[0], 0, 0, 0);
        oacc[0] = __builtin_amdgcn_mfma_f32_16x16x32_bf16(pa1, vf1, oacc[0], 0, 0, 0);
        oacc[1] = __builtin_amdgcn_mfma_f32_16x16x32_bf16(pa0, vf2, oacc[1], 0, 0, 0);
        oacc[1] = __builtin_amdgcn_mfma_f32_16x16x32_bf16(pa1, vf3, oacc[1], 0, 0, 0);
        oacc[2] = __builtin_amdgcn_mfma_f32_16x16x32_bf16(pa0, vf4, oacc[2], 0, 0, 0);
        oacc[2] = __builtin_amdgcn_mfma_f32_16x16x32_bf16(pa1, vf5, oacc[2], 0, 0, 0);
        oacc[3] = __builtin_amdgcn_mfma_f32_16x16x32_bf16(pa0, vf6, oacc[3], 0, 0, 0);
        oacc[3] = __builtin_amdgcn_mfma_f32_16x16x32_bf16(pa1, vf7, oacc[3], 0, 0, 0);
    }

    // ---- epilogue: O -> Ob bf16 (LDS transpose, wave-private) ----
#pragma unroll
    for (int ht = 0; ht < 4; ++ht)
#pragma unroll
        for (int i = 0; i < 4; ++i)
            P[wv][lg * 4 + i][ht * 16 + l15] = (__bf16)oacc[ht][i];
    const int arow = lane >> 2;
    const int aseg = lane & 3;
    uint4 o0 = *reinterpret_cast<const uint4*>(&P[wv][arow][aseg * 16]);
    uint4 o1 = *reinterpret_cast<const uint4*>(&P[wv][arow][aseg * 16 + 8]);
    const int b = bh >> 3, h = bh & 7;
    __bf16* dst = Ob + ((size_t)(b * LL + q0 + arow)) * DD + h * HD + aseg * 16;
    *reinterpret_cast<uint4*>(dst)     = o0;
    *reinterpret_cast<uint4*>(dst + 8) = o1;
}

// ---------------------------------------------------------------------------
// Kernel 3: out = Ob(bf16) @ Wo.T + bo -> fp32. grid (BL/64, 8), block 256.
// ---------------------------------------------------------------------------
__global__ __launch_bounds__(256) void oproj_kernel(
    const __bf16* __restrict__ Ob, const float* __restrict__ Wo,
    const float* __restrict__ bo, float* __restrict__ out)
{
    const int wid = threadIdx.x >> 6;
    const int lane = threadIdx.x & 63;
    const int l15 = lane & 15;
    const int lg  = lane >> 4;

    const int r0 = blockIdx.x * 64;
    const int c0 = blockIdx.y * 64 + wid * 16;

    f32x4 acc[4] = {};
    for (int k0 = 0; k0 < DD; k0 += 32) {
        bf16x8 bfrag = cvt8(&Wo[(size_t)(c0 + l15) * DD + k0 + lg * 8]);
#pragma unroll
        for (int mt = 0; mt < 4; ++mt) {
            bf16x8 afrag = *reinterpret_cast<const bf16x8*>(
                &Ob[(size_t)(r0 + mt * 16 + l15) * DD + k0 + lg * 8]);
            acc[mt] = __builtin_amdgcn_mfma_f32_16x16x32_bf16(afrag, bfrag, acc[mt], 0, 0, 0);
        }
    }
    const float bval = bo[c0 + l15];
#pragma unroll
    for (int mt = 0; mt < 4; ++mt)
#pragma unroll
        for (int i = 0; i < 4; ++i)
            out[(size_t)(r0 + mt * 16 + lg * 4 + i) * DD + c0 + l15] = acc[mt][i] + bval;
}

// ---------------------------------------------------------------------------
extern "C" void kernel_launch(void* const* d_in, const int* in_sizes, int n_in,
                              void* d_out, int out_size, void* d_ws, size_t ws_size,
                              hipStream_t stream) {
    const float* query = (const float*)d_in[0];
    const float* key_t = (const float*)d_in[1];
    const float* value = (const float*)d_in[2];
    const float* Wq = (const float*)d_in[3];
    const float* bq = (const float*)d_in[4];
    const float* Wk = (const float*)d_in[5];
    const float* bk = (const float*)d_in[6];
    const float* Wv = (const float*)d_in[7];
    const float* bv = (const float*)d_in[8];
    const float* Wo = (const float*)d_in[9];
    const float* bo = (const float*)d_in[10];

    float* out  = (float*)d_out;             // [B,L,D]
    float* attn = out + OUT_ELEMS;           // [B,H,L,L]

    char* ws = (char*)d_ws;
    __bf16* Qb = (__bf16*)(ws);                        //  8.39 MB
    __bf16* Kb = (__bf16*)(ws +  8388608);             //  8.39 MB
    __bf16* Vt = (__bf16*)(ws + 16777216);             //  8.39 MB
    __bf16* Ob = (__bf16*)(ws + 25165824);             //  8.39 MB
    __bf16* Xb = (__bf16*)(ws + 33554432);             // 25.2 MB

    // Zero the entire attn output via ROCm's fill path (d_out fill-BW witness).
    hipMemsetAsync(attn, 0, ATTN_ELEMS * sizeof(float), stream);

    cvt_kernel<<<dim3(3 * BL * DD / 8 / 256), 256, 0, stream>>>(query, key_t, value, Xb);
    qkv_kernel<<<dim3(BL / 64, DD / 64, 3), 256, 0, stream>>>(
        Xb, Wq, bq, Wk, bk, Wv, bv, Qb, Kb, Vt);
    attn_fused_kernel<<<dim3(BB * HH, LL / 64), 256, 0, stream>>>(Qb, Kb, Vt, Ob, attn);
    oproj_kernel<<<dim3(BL / 64, DD / 64), 256, 0, stream>>>(Ob, Wo, bo, out);
}

// Round 12
// 737.078 us; speedup vs baseline: 1.1378x; 1.1378x over previous
//
#include <hip/hip_runtime.h>
#include <hip/hip_bf16.h>

// B=2, L=4096, D=512, H=8, Hd=64, causal MHA, outputs (out, attn) fp32.
//
// ROOFLINE NOTE (R11 measurement): the attn region of d_out sustains only
// ~1.6 TB/s for writes — ROCm's own fillBufferAligned writing 1.074 GB to it
// took 668 µs (vs 6.5 TB/s for the same kernel on d_ws). The mandatory
// 1.09 GB of d_out traffic therefore floors the problem at ~677 µs; this
// kernel (735 µs total) is within ~8% of that including the dependent
// cvt/qkv/oproj side phases.

typedef __attribute__((ext_vector_type(8))) __bf16 bf16x8;
typedef __attribute__((ext_vector_type(4))) __bf16 bf16v4;
typedef __attribute__((ext_vector_type(4))) float f32x4;

constexpr int LL = 4096;
constexpr int DD = 512;
constexpr int HH = 8;
constexpr int HD = 64;
constexpr int BB = 2;
constexpr int BL = BB * LL;
constexpr size_t OUT_ELEMS = (size_t)BB * LL * DD;

static __device__ inline bf16x8 cvt8(const float* p) {
    float4 a = *reinterpret_cast<const float4*>(p);
    float4 b = *reinterpret_cast<const float4*>(p + 4);
    bf16x8 r;
    r[0] = (__bf16)a.x; r[1] = (__bf16)a.y; r[2] = (__bf16)a.z; r[3] = (__bf16)a.w;
    r[4] = (__bf16)b.x; r[5] = (__bf16)b.y; r[6] = (__bf16)b.z; r[7] = (__bf16)b.w;
    return r;
}

// ---------------------------------------------------------------------------
// Kernel 0: fp32 -> bf16 prepack of the three inputs.
// ---------------------------------------------------------------------------
__global__ __launch_bounds__(256) void cvt_kernel(
    const float* __restrict__ q, const float* __restrict__ k,
    const float* __restrict__ v, __bf16* __restrict__ o)
{
    constexpr size_t N = (size_t)BL * DD;
    size_t i = ((size_t)blockIdx.x * 256 + threadIdx.x) * 8;
    const float* src = q; size_t j = i;
    if (i >= 2 * N)      { src = v; j = i - 2 * N; }
    else if (i >= N)     { src = k; j = i - N; }
    *reinterpret_cast<bf16x8*>(&o[i]) = cvt8(&src[j]);
}

// ---------------------------------------------------------------------------
// Kernel 1: QKV projection from bf16 inputs. y = x @ W.T + b, bf16 out.
// z=0 -> Q [B,H,L,64]; z=1 -> K [B,H,L,64]; z=2 -> V^T [B,H,64,L].
// grid (BL/64, 8, 3), block 256.
// ---------------------------------------------------------------------------
__global__ __launch_bounds__(256) void qkv_kernel(
    const __bf16* __restrict__ Xb,
    const float* __restrict__ Wq, const float* __restrict__ bq,
    const float* __restrict__ Wk, const float* __restrict__ bk,
    const float* __restrict__ Wv, const float* __restrict__ bv,
    __bf16* __restrict__ Qb, __bf16* __restrict__ Kb, __bf16* __restrict__ Vt)
{
    const int z = blockIdx.z;
    const __bf16* x  = Xb + (size_t)z * BL * DD;
    const float* W   = (z == 0) ? Wq : (z == 1) ? Wk : Wv;
    const float* bia = (z == 0) ? bq : (z == 1) ? bk : bv;

    const int wid = threadIdx.x >> 6;
    const int lane = threadIdx.x & 63;
    const int l15 = lane & 15;
    const int lg  = lane >> 4;

    const int r0 = blockIdx.x * 64;
    const int cb = blockIdx.y;
    const int c0 = cb * 64 + wid * 16;

    f32x4 acc[4] = {};
    for (int k0 = 0; k0 < DD; k0 += 32) {
        bf16x8 bfrag = cvt8(&W[(size_t)(c0 + l15) * DD + k0 + lg * 8]);
#pragma unroll
        for (int mt = 0; mt < 4; ++mt) {
            bf16x8 afrag = *reinterpret_cast<const bf16x8*>(
                &x[(size_t)(r0 + mt * 16 + l15) * DD + k0 + lg * 8]);
            acc[mt] = __builtin_amdgcn_mfma_f32_16x16x32_bf16(afrag, bfrag, acc[mt], 0, 0, 0);
        }
    }

    __shared__ __bf16 T[64][72];
    const float bval = bia[c0 + l15];
#pragma unroll
    for (int mt = 0; mt < 4; ++mt)
#pragma unroll
        for (int i = 0; i < 4; ++i) {
            const float val = acc[mt][i] + bval;
            const int row = mt * 16 + lg * 4 + i;
            const int col = wid * 16 + l15;
            if (z == 2) T[col][row] = (__bf16)val;
            else        T[row][col] = (__bf16)val;
        }
    __syncthreads();

    const int tr  = threadIdx.x >> 2;
    const int seg = threadIdx.x & 3;
    uint4 v0 = *reinterpret_cast<const uint4*>(&T[tr][seg * 16]);
    uint4 v1 = *reinterpret_cast<const uint4*>(&T[tr][seg * 16 + 8]);
    const int b  = r0 >> 12;
    const int l0 = r0 & (LL - 1);
    if (z == 2) {
        __bf16* dst = Vt + ((size_t)(b * HH + cb) * HD + tr) * LL + l0 + seg * 16;
        *reinterpret_cast<uint4*>(dst)     = v0;
        *reinterpret_cast<uint4*>(dst + 8) = v1;
    } else {
        __bf16* base = (z == 0) ? Qb : Kb;
        __bf16* dst = base + ((size_t)(b * HH + cb) * LL + l0 + tr) * HD + seg * 16;
        *reinterpret_cast<uint4*>(dst)     = v0;
        *reinterpret_cast<uint4*>(dst + 8) = v1;
    }
}

// ---------------------------------------------------------------------------
// Kernel 2: FUSED causal attention. One WG per (bh, qb) 64-row block.
// Order: (a) zero-fill above-diagonal (stores drain under later compute),
// (b) pass 1: swapped QK (mfma(K,Q)) + exp -> row sums (2 shfl reduce),
// (c) pass 2: recompute QK, normalized P, direct fp32 attn store, PV via
// wave-private LDS P tile, (d) O epilogue -> Ob bf16.
// grid (16 bh, 64 qb-desc), block 256 (wave w owns rows w*16..+15).
// ---------------------------------------------------------------------------
__global__ __launch_bounds__(256) void attn_fused_kernel(
    const __bf16* __restrict__ Qb, const __bf16* __restrict__ Kb,
    const __bf16* __restrict__ Vt, __bf16* __restrict__ Ob,
    float* __restrict__ attn_out)
{
    const int bh = blockIdx.x;
    const int qb = 63 - blockIdx.y;          // heavy WGs dispatch first

    const int wv   = threadIdx.x >> 6;
    const int lane = threadIdx.x & 63;
    const int l15  = lane & 15;
    const int lg   = lane >> 4;

    float* A_out = attn_out + (size_t)bh * LL * LL;
    const int q0 = qb * 64 + wv * 16;
    const int qrow = q0 + l15;

    // ---- (a) zero-fill this wave's 16 rows, cols (qb+1)*64..4095 ----
    // 64 lanes x 16B = 1KB contiguous per instruction; fire-and-forget.
    {
        const f32x4 z4 = {0.f, 0.f, 0.f, 0.f};
        const int c0 = (qb + 1) * 64;
#pragma unroll 1
        for (int r = 0; r < 16; ++r) {
            float* row = A_out + (size_t)(q0 + r) * LL;
            for (int c = c0 + lane * 4; c < LL; c += 256)
                *reinterpret_cast<f32x4*>(row + c) = z4;
        }
    }

    const __bf16* Qh = Qb + (size_t)bh * LL * HD;
    const __bf16* Kh = Kb + (size_t)bh * LL * HD;
    const __bf16* Vh = Vt + (size_t)bh * HD * LL;

    __shared__ __bf16 P[4][16][72];          // wave-private P tile

    const bf16x8 qf0 = *reinterpret_cast<const bf16x8*>(&Qh[(size_t)qrow * HD + lg * 8]);
    const bf16x8 qf1 = *reinterpret_cast<const bf16x8*>(&Qh[(size_t)qrow * HD + 32 + lg * 8]);
    const float SC = 0.125f * 1.44269504088896f;   // scale * log2(e)

    // ---- (b) pass 1: row sums ----
    float rs = 0.f;
    for (int kb = 0; kb <= qb; ++kb) {
        const __bf16* kp = &Kh[((size_t)kb * 64 + l15) * HD + lg * 8];
        f32x4 s[4] = {};
#pragma unroll
        for (int kt = 0; kt < 4; ++kt) {
            bf16x8 k0 = *reinterpret_cast<const bf16x8*>(kp + (size_t)kt * 16 * HD);
            bf16x8 k1 = *reinterpret_cast<const bf16x8*>(kp + (size_t)kt * 16 * HD + 32);
            s[kt] = __builtin_amdgcn_mfma_f32_16x16x32_bf16(k0, qf0, s[kt], 0, 0, 0);
            s[kt] = __builtin_amdgcn_mfma_f32_16x16x32_bf16(k1, qf1, s[kt], 0, 0, 0);
        }
        const bool diag = (kb == qb);
#pragma unroll
        for (int kt = 0; kt < 4; ++kt)
#pragma unroll
            for (int i = 0; i < 4; ++i) {
                float e = exp2f(s[kt][i] * SC);
                if (diag && (kb * 64 + kt * 16 + lg * 4 + i) > qrow) e = 0.f;
                rs += e;
            }
    }
    rs += __shfl_xor(rs, 16, 64);
    rs += __shfl_xor(rs, 32, 64);
    const float llog = -log2f(rs);

    // ---- (c) pass 2: attn write + PV ----
    f32x4 oacc[4] = {};
    for (int kb = 0; kb <= qb; ++kb) {
        const __bf16* kp = &Kh[((size_t)kb * 64 + l15) * HD + lg * 8];
        const __bf16* vp = &Vh[(size_t)l15 * LL + (size_t)kb * 64 + lg * 8];
        // V loads issue first; consumed after the P chain
        bf16x8 vf0 = *reinterpret_cast<const bf16x8*>(vp + (size_t)0 * 16 * LL);
        bf16x8 vf1 = *reinterpret_cast<const bf16x8*>(vp + (size_t)0 * 16 * LL + 32);
        bf16x8 vf2 = *reinterpret_cast<const bf16x8*>(vp + (size_t)1 * 16 * LL);
        bf16x8 vf3 = *reinterpret_cast<const bf16x8*>(vp + (size_t)1 * 16 * LL + 32);
        bf16x8 vf4 = *reinterpret_cast<const bf16x8*>(vp + (size_t)2 * 16 * LL);
        bf16x8 vf5 = *reinterpret_cast<const bf16x8*>(vp + (size_t)2 * 16 * LL + 32);
        bf16x8 vf6 = *reinterpret_cast<const bf16x8*>(vp + (size_t)3 * 16 * LL);
        bf16x8 vf7 = *reinterpret_cast<const bf16x8*>(vp + (size_t)3 * 16 * LL + 32);

        f32x4 s[4] = {};
#pragma unroll
        for (int kt = 0; kt < 4; ++kt) {
            bf16x8 k0 = *reinterpret_cast<const bf16x8*>(kp + (size_t)kt * 16 * HD);
            bf16x8 k1 = *reinterpret_cast<const bf16x8*>(kp + (size_t)kt * 16 * HD + 32);
            s[kt] = __builtin_amdgcn_mfma_f32_16x16x32_bf16(k0, qf0, s[kt], 0, 0, 0);
            s[kt] = __builtin_amdgcn_mfma_f32_16x16x32_bf16(k1, qf1, s[kt], 0, 0, 0);
        }
        const bool diag = (kb == qb);
#pragma unroll
        for (int kt = 0; kt < 4; ++kt) {
            float e0 = exp2f(fmaf(s[kt][0], SC, llog));
            float e1 = exp2f(fmaf(s[kt][1], SC, llog));
            float e2 = exp2f(fmaf(s[kt][2], SC, llog));
            float e3 = exp2f(fmaf(s[kt][3], SC, llog));
            if (diag) {
                const int kc = kb * 64 + kt * 16 + lg * 4;
                if (kc + 0 > qrow) e0 = 0.f;
                if (kc + 1 > qrow) e1 = 0.f;
                if (kc + 2 > qrow) e2 = 0.f;
                if (kc + 3 > qrow) e3 = 0.f;
            }
            // direct fp32 attn store (lane-local row, 16B per lane)
            f32x4 ev = {e0, e1, e2, e3};
            *reinterpret_cast<f32x4*>(
                &A_out[(size_t)qrow * LL + kb * 64 + kt * 16 + lg * 4]) = ev;
            // bf16 pack for PV
            bf16v4 pk;
            pk[0] = (__bf16)e0; pk[1] = (__bf16)e1;
            pk[2] = (__bf16)e2; pk[3] = (__bf16)e3;
            *reinterpret_cast<bf16v4*>(&P[wv][l15][kt * 16 + lg * 4]) = pk;
        }
        const bf16x8 pa0 = *reinterpret_cast<const bf16x8*>(&P[wv][l15][lg * 8]);
        const bf16x8 pa1 = *reinterpret_cast<const bf16x8*>(&P[wv][l15][32 + lg * 8]);
        oacc[0] = __builtin_amdgcn_mfma_f32_16x16x32_bf16(pa0, vf0, oacc[0], 0, 0, 0);
        oacc[0] = __builtin_amdgcn_mfma_f32_16x16x32_bf16(pa1, vf1, oacc[0], 0, 0, 0);
        oacc[1] = __builtin_amdgcn_mfma_f32_16x16x32_bf16(pa0, vf2, oacc[1], 0, 0, 0);
        oacc[1] = __builtin_amdgcn_mfma_f32_16x16x32_bf16(pa1, vf3, oacc[1], 0, 0, 0);
        oacc[2] = __builtin_amdgcn_mfma_f32_16x16x32_bf16(pa0, vf4, oacc[2], 0, 0, 0);
        oacc[2] = __builtin_amdgcn_mfma_f32_16x16x32_bf16(pa1, vf5, oacc[2], 0, 0, 0);
        oacc[3] = __builtin_amdgcn_mfma_f32_16x16x32_bf16(pa0, vf6, oacc[3], 0, 0, 0);
        oacc[3] = __builtin_amdgcn_mfma_f32_16x16x32_bf16(pa1, vf7, oacc[3], 0, 0, 0);
    }

    // ---- (d) O epilogue -> Ob bf16 (LDS transpose, wave-private) ----
#pragma unroll
    for (int ht = 0; ht < 4; ++ht)
#pragma unroll
        for (int i = 0; i < 4; ++i)
            P[wv][lg * 4 + i][ht * 16 + l15] = (__bf16)oacc[ht][i];
    const int arow = lane >> 2;
    const int aseg = lane & 3;
    uint4 o0 = *reinterpret_cast<const uint4*>(&P[wv][arow][aseg * 16]);
    uint4 o1 = *reinterpret_cast<const uint4*>(&P[wv][arow][aseg * 16 + 8]);
    const int b = bh >> 3, h = bh & 7;
    __bf16* dst = Ob + ((size_t)(b * LL + q0 + arow)) * DD + h * HD + aseg * 16;
    *reinterpret_cast<uint4*>(dst)     = o0;
    *reinterpret_cast<uint4*>(dst + 8) = o1;
}

// ---------------------------------------------------------------------------
// Kernel 3: out = Ob(bf16) @ Wo.T + bo -> fp32. grid (BL/64, 8), block 256.
// ---------------------------------------------------------------------------
__global__ __launch_bounds__(256) void oproj_kernel(
    const __bf16* __restrict__ Ob, const float* __restrict__ Wo,
    const float* __restrict__ bo, float* __restrict__ out)
{
    const int wid = threadIdx.x >> 6;
    const int lane = threadIdx.x & 63;
    const int l15 = lane & 15;
    const int lg  = lane >> 4;

    const int r0 = blockIdx.x * 64;
    const int c0 = blockIdx.y * 64 + wid * 16;

    f32x4 acc[4] = {};
    for (int k0 = 0; k0 < DD; k0 += 32) {
        bf16x8 bfrag = cvt8(&Wo[(size_t)(c0 + l15) * DD + k0 + lg * 8]);
#pragma unroll
        for (int mt = 0; mt < 4; ++mt) {
            bf16x8 afrag = *reinterpret_cast<const bf16x8*>(
                &Ob[(size_t)(r0 + mt * 16 + l15) * DD + k0 + lg * 8]);
            acc[mt] = __builtin_amdgcn_mfma_f32_16x16x32_bf16(afrag, bfrag, acc[mt], 0, 0, 0);
        }
    }
    const float bval = bo[c0 + l15];
#pragma unroll
    for (int mt = 0; mt < 4; ++mt)
#pragma unroll
        for (int i = 0; i < 4; ++i)
            out[(size_t)(r0 + mt * 16 + lg * 4 + i) * DD + c0 + l15] = acc[mt][i] + bval;
}

// ---------------------------------------------------------------------------
extern "C" void kernel_launch(void* const* d_in, const int* in_sizes, int n_in,
                              void* d_out, int out_size, void* d_ws, size_t ws_size,
                              hipStream_t stream) {
    const float* query = (const float*)d_in[0];
    const float* key_t = (const float*)d_in[1];
    const float* value = (const float*)d_in[2];
    const float* Wq = (const float*)d_in[3];
    const float* bq = (const float*)d_in[4];
    const float* Wk = (const float*)d_in[5];
    const float* bk = (const float*)d_in[6];
    const float* Wv = (const float*)d_in[7];
    const float* bv = (const float*)d_in[8];
    const float* Wo = (const float*)d_in[9];
    const float* bo = (const float*)d_in[10];

    float* out  = (float*)d_out;             // [B,L,D]
    float* attn = out + OUT_ELEMS;           // [B,H,L,L]

    char* ws = (char*)d_ws;
    __bf16* Qb = (__bf16*)(ws);                        //  8.39 MB
    __bf16* Kb = (__bf16*)(ws +  8388608);             //  8.39 MB
    __bf16* Vt = (__bf16*)(ws + 16777216);             //  8.39 MB
    __bf16* Ob = (__bf16*)(ws + 25165824);             //  8.39 MB
    __bf16* Xb = (__bf16*)(ws + 33554432);             // 25.2 MB

    cvt_kernel<<<dim3(3 * BL * DD / 8 / 256), 256, 0, stream>>>(query, key_t, value, Xb);
    qkv_kernel<<<dim3(BL / 64, DD / 64, 3), 256, 0, stream>>>(
        Xb, Wq, bq, Wk, bk, Wv, bv, Qb, Kb, Vt);
    attn_fused_kernel<<<dim3(BB * HH, LL / 64), 256, 0, stream>>>(Qb, Kb, Vt, Ob, attn);
    oproj_kernel<<<dim3(BL / 64, DD / 64), 256, 0, stream>>>(Ob, Wo, bo, out);
}